// Round 2
// baseline (104.510 us; speedup 1.0000x reference)
//
#include <hip/hip_runtime.h>

// DensityLoss: B=8, N=4096, radius=0.1, NSAMPLE=9, TOPK=5, H=0.12, EPS=1e-12
// Output: scalar mean over [B,N,TOPK-1] of (RADIUS - sqrt(ds)*exp(-ds/H^2))
//
// R7: column-block query kernel. R6's K2 was latency-bound (0.5 waves/SIMD,
// exposed L2 gather latency) and VALU-bound (45-inst index-insert network
// fired on ~90% of wave iterations). Restructure:
//   K2 block = (batch, x,y column) -> 800 blocks x 64 lanes; lane = query.
//   - 3x3 column neighborhood (~370 pts) staged once into LDS (9 contiguous
//     segment copies) -> ds_read_b128 instead of L2 gathers.
//   - Scan phase appends hits (idx,d2) to a per-lane LDS row (~4 masked
//     insts); the verified 9-deep index-insert runs per HIT (~17/query) in a
//     post-pass, not per candidate.
//   - Per-query z-window (cells cz-1..cz+1 of each column). Candidates outside
//     the window are provably out of ball (|dz|>R strictly), so trimming is
//     exact. Same cell_coord/d2/insert/pad/sort5/formula as verified R6.
//   K1 unchanged except: out-zero fused in (drops memset launch), global
//   loads issued before histogram zeroing.

#define NB 8
#define NPTS 4096
#define NS 9
#define RAD2 0.01f
#define H2 0.0144f
#define EPSV 1e-12f
#define SCALE (1.0f / 131072.0f)   // 1/(B*N*(TOPK-1)) = 1/(8*4096*4)
#define NCELL 1000
#define CS_STRIDE 1008
#define SENT 0x7fffffff
#define CAP 64        // per-query hit buffer (max in-ball hits ~45 for this input)
#define ROWW 65       // padded row stride (bank spread)
#define REGCAP 768    // staged region capacity (avg ~370, tail ~465)

__device__ __forceinline__ int cell_coord(float v) {
    int c = (int)(v * 10.0f);
    return min(max(c, 0), 9);
}

// ---------------- K1: counting sort into 10x10x10 cells, one block/batch ----
__global__ __launch_bounds__(1024) void bin_kernel(
    const float* __restrict__ pred, float4* __restrict__ sorted,
    int* __restrict__ cellStart, float* __restrict__ out) {
    __shared__ int hist[NCELL];
    __shared__ int waveTot[16];
    const int tid  = threadIdx.x;
    const int lane = tid & 63;
    const int wid  = tid >> 6;
    const int b    = blockIdx.x;

    // Issue global loads first so HBM latency hides under the hist zeroing.
    const float* src = pred + (size_t)b * (NPTS * 3) + tid * 12;
    float4 a0 = *(const float4*)(src);
    float4 a1 = *(const float4*)(src + 4);
    float4 a2 = *(const float4*)(src + 8);

    if (b == 0 && tid == 0) *out = 0.0f;   // replaces hipMemsetAsync(out)

    for (int i = tid; i < NCELL; i += 1024) hist[i] = 0;
    __syncthreads();

    float xs[4] = {a0.x, a0.w, a1.z, a2.y};
    float ys[4] = {a0.y, a1.x, a1.w, a2.z};
    float zs[4] = {a0.z, a1.y, a2.x, a2.w};
    int cell[4];
    #pragma unroll
    for (int k = 0; k < 4; ++k) {
        cell[k] = (cell_coord(xs[k]) * 10 + cell_coord(ys[k])) * 10 + cell_coord(zs[k]);
        atomicAdd(&hist[cell[k]], 1);
    }
    __syncthreads();

    // Block-wide exclusive scan over the 1000 counters.
    int v = (tid < NCELL) ? hist[tid] : 0;
    int incl = v;
    #pragma unroll
    for (int off = 1; off < 64; off <<= 1) {
        int n = __shfl_up(incl, off, 64);
        if (lane >= off) incl += n;
    }
    if (lane == 63) waveTot[wid] = incl;
    __syncthreads();
    if (tid == 0) {
        int run = 0;
        for (int w = 0; w < 16; ++w) { int t = waveTot[w]; waveTot[w] = run; run += t; }
    }
    __syncthreads();
    int excl = incl - v + waveTot[wid];
    if (tid < NCELL) cellStart[b * CS_STRIDE + tid] = excl;
    if (tid == 0)    cellStart[b * CS_STRIDE + NCELL] = NPTS;
    __syncthreads();
    if (tid < NCELL) hist[tid] = excl;   // reuse as scatter cursors
    __syncthreads();

    float4* dst = sorted + (size_t)b * NPTS;
    #pragma unroll
    for (int k = 0; k < 4; ++k) {
        int slot = atomicAdd(&hist[cell[k]], 1);
        dst[slot] = (float4){xs[k], ys[k], zs[k], __int_as_float(tid * 4 + k)};
    }
}

// ---------------- K2: column block, LDS-staged region, per-lane query -------
__global__ __launch_bounds__(64) void query_kernel(
    const float4* __restrict__ sorted, const int* __restrict__ cellStart,
    float* __restrict__ out) {
    __shared__ __align__(16) float4 reg[REGCAP];   // staged 3x3-column region
    __shared__ int csl[99];        // csl[c*11+z] = cellStart of (col c, zcell z)
    __shared__ int segBase[9];     // region offset of column c (-1 => unstaged)
    __shared__ int2 hits[64][ROWW];// per-lane hit rows (idx, d2 bits)

    const int tid = threadIdx.x;
    const int b   = blockIdx.x / 100;
    const int col = blockIdx.x % 100;
    const int cx  = col / 10, cy = col % 10;
    const int* csg = cellStart + b * CS_STRIDE;
    const float4* P = sorted + (size_t)b * NPTS;

    // Stage the 9 columns' z-boundaries (invalid columns -> 0 -> empty).
    for (int i = tid; i < 99; i += 64) {
        int c = i / 11, z = i - c * 11;
        int xx = cx + c / 3 - 1, yy = cy + (c % 3) - 1;
        bool valid = (xx >= 0 && xx <= 9 && yy >= 0 && yy <= 9);
        csl[i] = valid ? csg[(xx * 10 + yy) * 10 + z] : 0;
    }
    __syncthreads();

    // Stage region: 9 contiguous segment copies, global -> LDS.
    {
        int roff = 0;
        for (int c = 0; c < 9; ++c) {
            int gs = csl[c * 11], len = csl[c * 11 + 10] - gs;
            bool fit = (roff + len <= REGCAP);
            if (tid == 0) segBase[c] = fit ? roff : -1;
            if (fit) {
                for (int i = tid; i < len; i += 64) reg[roff + i] = P[gs + i];
                roff += len;
            }
        }
    }
    __syncthreads();

    const int qs = csl[4 * 11], qe = csl[4 * 11 + 10];   // own column's queries
    float accT = 0.0f;

    for (int q0 = qs; q0 < qe; q0 += 64) {
        const int q = q0 + tid;
        const bool active = (q < qe);
        float qx = 0.f, qy = 0.f, qz = 0.f;
        int z0 = 0, z1 = -1;                  // empty window for inactive lanes
        if (active) {
            int sb4 = segBase[4];
            float4 me = (sb4 >= 0) ? reg[sb4 + (q - qs)] : P[q];
            qx = me.x; qy = me.y; qz = me.z;
            int cz = cell_coord(qz);
            z0 = max(cz - 1, 0); z1 = min(cz + 1, 9);
        }
        int2* myrow = hits[tid];
        int mycnt = 0;

        // Scan: per column, the query's z-window; hits append to own LDS row.
        for (int c = 0; c < 9; ++c) {
            const int gs = csl[c * 11];
            const int s  = csl[c * 11 + z0];
            const int e  = csl[c * 11 + z1 + 1];
            const int sb = segBase[c];
            if (sb >= 0) {
                const float4* rp = reg + (sb - gs);
                for (int k = s; k < e; ++k) {
                    float4 cd = rp[k];
                    float dx = cd.x - qx, dy = cd.y - qy, dz = cd.z - qz;
                    float d2 = dx * dx + dy * dy + dz * dz;
                    if (d2 <= RAD2) {
                        if (mycnt < CAP)
                            myrow[mycnt] = (int2){__float_as_int(cd.w), __float_as_int(d2)};
                        mycnt++;
                    }
                }
            } else {                           // overflow fallback: read global
                for (int k = s; k < e; ++k) {
                    float4 cd = P[k];
                    float dx = cd.x - qx, dy = cd.y - qy, dz = cd.z - qz;
                    float d2 = dx * dx + dy * dy + dz * dz;
                    if (d2 <= RAD2) {
                        if (mycnt < CAP)
                            myrow[mycnt] = (int2){__float_as_int(cd.w), __float_as_int(d2)};
                        mycnt++;
                    }
                }
            }
        }

        // Post-select: 9 smallest original indices via verified insert network.
        int   I[NS];
        float D[NS];
        #pragma unroll
        for (int t = 0; t < NS; ++t) { I[t] = SENT; D[t] = 0.0f; }
        const int n = (mycnt < CAP) ? mycnt : CAP;
        for (int h = 0; h < n; ++h) {
            int2 pr = myrow[h];
            int ci = pr.x; float dd = __int_as_float(pr.y);
            if (ci < I[NS - 1]) {
                int ii = ci; float d = dd;
                #pragma unroll
                for (int t = 0; t < NS; ++t) {
                    bool sw = ii < I[t];
                    int oI = I[t]; float oD = D[t];
                    I[t] = sw ? ii : oI;  D[t] = sw ? d : oD;
                    ii   = sw ? oI : ii;  d    = sw ? oD : d;
                }
            }
        }

        // Pad missing slots with the first (smallest-index) hit's distance.
        // Active lanes always have >=1 hit (self, d2=0).
        #pragma unroll
        for (int t = 1; t < NS; ++t) if (I[t] == SENT) D[t] = D[0];

        // Partial selection sort: 5 smallest ascending into D[0..4].
        #pragma unroll
        for (int i = 0; i < 5; ++i) {
            #pragma unroll
            for (int j = i + 1; j < NS; ++j) {
                float lo = fminf(D[i], D[j]);
                float hi = fmaxf(D[i], D[j]);
                D[i] = lo; D[j] = hi;
            }
        }
        if (active) {
            float acc = 0.0f;
            #pragma unroll
            for (int i = 1; i < 5; ++i) {
                float cc = (D[i] < EPSV) ? EPSV : D[i];
                acc += 0.1f - sqrtf(cc) * expf(-cc / H2);
            }
            accT += acc;
        }
    }

    #pragma unroll
    for (int off = 32; off >= 1; off >>= 1)
        accT += __shfl_down(accT, off, 64);
    if (tid == 0) atomicAdd(out, accT * SCALE);
}

extern "C" void kernel_launch(void* const* d_in, const int* in_sizes, int n_in,
                              void* d_out, int out_size, void* d_ws, size_t ws_size,
                              hipStream_t stream) {
    const float* pred = (const float*)d_in[0];
    float* out = (float*)d_out;
    float4* sorted = (float4*)d_ws;
    int* cellStart = (int*)((char*)d_ws + (size_t)NB * NPTS * sizeof(float4));
    // out is zeroed inside bin_kernel (block 0) -- no separate memset launch.
    bin_kernel<<<dim3(NB), dim3(1024), 0, stream>>>(pred, sorted, cellStart, out);
    query_kernel<<<dim3(NB * 100), dim3(64), 0, stream>>>(sorted, cellStart, out);
}

// Round 3
// 91.958 us; speedup vs baseline: 1.1365x; 1.1365x over previous
//
#include <hip/hip_runtime.h>

// DensityLoss: B=8, N=4096, radius=0.1, NSAMPLE=9, TOPK=5, H=0.12, EPS=1e-12
// Output: scalar mean over [B,N,TOPK-1] of (RADIUS - sqrt(ds)*exp(-ds/H^2))
//
// R8: binned + wave-parallel. R7's lane=query structure capped at 512 waves
// (0.5/SIMD, latency-bound, 8% VALUBusy). Now: wave = 4 consecutive
// cell-sorted queries, 64 lanes stride the shared 27-cell candidate superset
// -> 8192 waves, coalesced L2 reads, no LDS staging (22KB/block).
//   - <=40 column segments flattened into one virtual list (prefix table +
//     binary search) so lanes stay ~full each iteration (~150 cands, 2-3 its).
//   - Hits: verified R5 ballot/mbcnt rank append of key=(ci<<6|slot) + d2
//     into per-query LDS rows (CAP 64, guarded).
//   - Selection: bitonic-32 on keys (2 queries/pass, one per 32-lane half)
//     -> 9 smallest original indices; fetch d2; bitonic-16 on distances ->
//     lanes 1..4 are ranks 2..5. Slow wave-min path if a query has >32 hits
//     (~13/32768 queries). Padding=d(smallest-index hit), EPS clamp, formula
//     identical to verified R5-R7.
// K1 (bin_kernel) unchanged from verified R7.

#define NB 8
#define NPTS 4096
#define NS 9
#define RAD2 0.01f
#define H2 0.0144f
#define EPSV 1e-12f
#define SCALE (1.0f / 131072.0f)   // 1/(B*N*(TOPK-1)) = 1/(8*4096*4)
#define NCELL 1000
#define CS_STRIDE 1008
#define CAP 64
#define MAXSEG 41

__device__ __forceinline__ int cell_coord(float v) {
    int c = (int)(v * 10.0f);
    return min(max(c, 0), 9);
}

// ---------------- K1: counting sort into 10x10x10 cells, one block/batch ----
__global__ __launch_bounds__(1024) void bin_kernel(
    const float* __restrict__ pred, float4* __restrict__ sorted,
    int* __restrict__ cellStart, float* __restrict__ out) {
    __shared__ int hist[NCELL];
    __shared__ int waveTot[16];
    const int tid  = threadIdx.x;
    const int lane = tid & 63;
    const int wid  = tid >> 6;
    const int b    = blockIdx.x;

    // Issue global loads first so HBM latency hides under the hist zeroing.
    const float* src = pred + (size_t)b * (NPTS * 3) + tid * 12;
    float4 a0 = *(const float4*)(src);
    float4 a1 = *(const float4*)(src + 4);
    float4 a2 = *(const float4*)(src + 8);

    if (b == 0 && tid == 0) *out = 0.0f;   // replaces hipMemsetAsync(out)

    for (int i = tid; i < NCELL; i += 1024) hist[i] = 0;
    __syncthreads();

    float xs[4] = {a0.x, a0.w, a1.z, a2.y};
    float ys[4] = {a0.y, a1.x, a1.w, a2.z};
    float zs[4] = {a0.z, a1.y, a2.x, a2.w};
    int cell[4];
    #pragma unroll
    for (int k = 0; k < 4; ++k) {
        cell[k] = (cell_coord(xs[k]) * 10 + cell_coord(ys[k])) * 10 + cell_coord(zs[k]);
        atomicAdd(&hist[cell[k]], 1);
    }
    __syncthreads();

    // Block-wide exclusive scan over the 1000 counters.
    int v = (tid < NCELL) ? hist[tid] : 0;
    int incl = v;
    #pragma unroll
    for (int off = 1; off < 64; off <<= 1) {
        int n = __shfl_up(incl, off, 64);
        if (lane >= off) incl += n;
    }
    if (lane == 63) waveTot[wid] = incl;
    __syncthreads();
    if (tid == 0) {
        int run = 0;
        for (int w = 0; w < 16; ++w) { int t = waveTot[w]; waveTot[w] = run; run += t; }
    }
    __syncthreads();
    int excl = incl - v + waveTot[wid];
    if (tid < NCELL) cellStart[b * CS_STRIDE + tid] = excl;
    if (tid == 0)    cellStart[b * CS_STRIDE + NCELL] = NPTS;
    __syncthreads();
    if (tid < NCELL) hist[tid] = excl;   // reuse as scatter cursors
    __syncthreads();

    float4* dst = sorted + (size_t)b * NPTS;
    #pragma unroll
    for (int k = 0; k < 4; ++k) {
        int slot = atomicAdd(&hist[cell[k]], 1);
        dst[slot] = (float4){xs[k], ys[k], zs[k], __int_as_float(tid * 4 + k)};
    }
}

// ---- hit append: R5-verified ballot/mbcnt rank logic, per query -----------
#define QSTEP(QV, CQ, RK, RD) {                                              \
    float dx = cd.x - QV.x, dy = cd.y - QV.y, dz = cd.z - QV.z;              \
    float d2 = dx * dx + dy * dy + dz * dz;                                  \
    bool hit = act && (d2 <= RAD2);                                          \
    unsigned long long m = __ballot(hit);                                    \
    if (m) {                                                                 \
        if (hit) {                                                           \
            unsigned r = __builtin_amdgcn_mbcnt_lo((unsigned)m, 0u);         \
            r = __builtin_amdgcn_mbcnt_hi((unsigned)(m >> 32), r);           \
            int slot = CQ + (int)r;                                          \
            if (slot < CAP) {                                                \
                (RK)[slot] = ((unsigned)ci << 6) | (unsigned)slot;           \
                (RD)[slot] = d2;                                             \
            }                                                                \
        }                                                                    \
        CQ += (int)__popcll(m);                                              \
    } }

// ---------------- K2: wave = 4 sorted queries, lanes over candidates --------
__global__ __launch_bounds__(512, 4) void query_kernel(
    const float4* __restrict__ sorted, const int* __restrict__ cellStart,
    float* __restrict__ out) {
    __shared__ int cs[NCELL + 1];
    __shared__ unsigned krow[32][CAP];     // per-query hit keys (ci<<6|slot)
    __shared__ float    drow[32][CAP];     // per-query hit d2
    __shared__ int sPref[8][MAXSEG + 1];   // per-wave segment prefix sums
    __shared__ int sBase[8][MAXSEG];       // global_start - prefix per segment
    __shared__ float blockAcc;

    const int tid  = threadIdx.x;
    const int lane = tid & 63;
    const int wid  = tid >> 6;
    const int j    = lane & 31;            // index within 32-lane half
    const int h    = lane >> 5;            // half id
    const int b    = blockIdx.x >> 7;      // 128 blocks per batch
    const int qbase = ((blockIdx.x & 127) << 5) + (wid << 2);  // sorted idx

    const int* csg = cellStart + b * CS_STRIDE;
    for (int i = tid; i <= NCELL; i += 512) cs[i] = csg[i];
    if (tid == 0) blockAcc = 0.0f;
    __syncthreads();

    const float4* P = sorted + (size_t)b * NPTS;
    const float4 Q0 = P[qbase], Q1 = P[qbase + 1];
    const float4 Q2 = P[qbase + 2], Q3 = P[qbase + 3];

    // Wave-uniform bbox of the 4 query cells, +-1, clamped.
    int ax = cell_coord(Q0.x), bx = cell_coord(Q1.x), gx = cell_coord(Q2.x), dx_ = cell_coord(Q3.x);
    int ay = cell_coord(Q0.y), by = cell_coord(Q1.y), gy = cell_coord(Q2.y), dy_ = cell_coord(Q3.y);
    int az = cell_coord(Q0.z), bz = cell_coord(Q1.z), gz = cell_coord(Q2.z), dz_ = cell_coord(Q3.z);
    const int x0 = max(min(min(ax, bx), min(gx, dx_)) - 1, 0);
    const int x1 = min(max(max(ax, bx), max(gx, dx_)) + 1, 9);
    const int y0 = max(min(min(ay, by), min(gy, dy_)) - 1, 0);
    const int y1 = min(max(max(ay, by), max(gy, dy_)) + 1, 9);
    const int z0 = max(min(min(az, bz), min(gz, dz_)) - 1, 0);
    const int z1 = min(max(max(az, bz), max(gz, dz_)) + 1, 9);

    // Flatten non-empty column segments [z0..z1] into one virtual list.
    int ncol = 0, tot = 0;
    for (int xx = x0; xx <= x1; ++xx)
        for (int yy = y0; yy <= y1; ++yy) {
            int cb = (xx * 10 + yy) * 10;
            int s = cs[cb + z0], e = cs[cb + z1 + 1];
            if (e > s && ncol < MAXSEG) {
                if (lane == 0) { sPref[wid][ncol] = tot; sBase[wid][ncol] = s - tot; }
                tot += e - s; ncol++;
            }
        }
    if (lane == 0) sPref[wid][ncol] = tot;

    unsigned* rk = &krow[wid << 2][0];     // 4 contiguous rows for this wave
    float*    rd = &drow[wid << 2][0];

    int c0 = 0, c1 = 0, c2 = 0, c3 = 0;
    for (int t0 = 0; t0 < tot; t0 += 64) {
        const int t = t0 + lane;
        const bool act = t < tot;
        int c = 0;
        #pragma unroll
        for (int w = 32; w >= 1; w >>= 1) {
            int m2 = c + w;
            if (m2 <= ncol - 1 && sPref[wid][m2] <= t) c = m2;
        }
        int gi = sBase[wid][c] + t;
        gi = act ? gi : qbase;             // safe in-bounds addr for idle lanes
        const float4 cd = P[gi];
        const int ci = __float_as_int(cd.w);
        QSTEP(Q0, c0, rk,           rd);
        QSTEP(Q1, c1, rk + CAP,     rd + CAP);
        QSTEP(Q2, c2, rk + 2 * CAP, rd + 2 * CAP);
        QSTEP(Q3, c3, rk + 3 * CAP, rd + 3 * CAP);
    }

    float accW = 0.0f;
    #pragma unroll
    for (int p = 0; p < 2; ++p) {
        const int nA = min(p ? c2 : c0, CAP);
        const int nB = min(p ? c3 : c1, CAP);
        const int rbase = (wid << 2) + (p << 1);
        const bool slow = (nA > 32) || (nB > 32);
        if (!slow) {
            // Fast path: each 32-lane half selects for one query.
            const int n  = h ? nB : nA;    // n >= 1 (self-hit, d2 = 0)
            const int qq = rbase + h;
            unsigned key = (j < n) ? krow[qq][j] : 0xFFFFFFFFu;
            #pragma unroll
            for (int k = 2; k <= 32; k <<= 1)
                #pragma unroll
                for (int s = k >> 1; s > 0; s >>= 1) {
                    unsigned o = __shfl_xor(key, s, 64);
                    bool keepmin = (((j & s) == 0) == ((j & k) == 0));
                    unsigned mn = min(key, o), mx = max(key, o);
                    key = keepmin ? mn : mx;
                }
            // lanes 0..8 now hold the 9 smallest indices (ascending).
            unsigned slot = key & 63u;
            bool valid = (key != 0xFFFFFFFFu);
            float dv = drow[qq][slot];
            float dfirst = __shfl(dv, h << 5, 64);   // d of smallest-index hit
            float d = valid ? dv : dfirst;           // pad semantics (ref)
            if (j >= NS) d = 1e30f;
            #pragma unroll
            for (int k = 2; k <= 16; k <<= 1)
                #pragma unroll
                for (int s = k >> 1; s > 0; s >>= 1) {
                    float o = __shfl_xor(d, s, 64);
                    bool keepmin = (((j & s) == 0) == ((j & k) == 0));
                    float mn = fminf(d, o), mx = fmaxf(d, o);
                    d = keepmin ? mn : mx;
                }
            // ascending distances in j=0..8; ranks 2..5 are j=1..4.
            if (j >= 1 && j <= 4) {
                float cc = (d < EPSV) ? EPSV : d;
                accW += 0.1f - sqrtf(cc) * expf(-cc / H2);
            }
        } else {
            // Slow path (>32 hits, ~13/32768 queries): 9x wave-min extraction.
            #pragma unroll
            for (int t2 = 0; t2 < 2; ++t2) {
                const int qq = rbase + t2;
                const int n = t2 ? nB : nA;
                unsigned kk = (lane < n) ? krow[qq][lane] : 0xFFFFFFFFu;
                float D[NS]; float dfirst = 0.0f;
                #pragma unroll
                for (int jx = 0; jx < NS; ++jx) {
                    unsigned tm = kk;
                    #pragma unroll
                    for (int off = 32; off >= 1; off >>= 1) {
                        unsigned o = __shfl_xor(tm, off, 64);
                        tm = min(tm, o);
                    }
                    if (kk == tm) kk = 0xFFFFFFFFu;  // mark extracted
                    bool ex = (tm == 0xFFFFFFFFu);
                    float dv = drow[qq][tm & 63u];
                    float dd = ex ? dfirst : dv;
                    if (jx == 0) dfirst = dd;
                    D[jx] = dd;
                }
                #pragma unroll
                for (int i = 0; i < 5; ++i)
                    #pragma unroll
                    for (int jj = i + 1; jj < NS; ++jj) {
                        float lo = fminf(D[i], D[jj]);
                        float hi = fmaxf(D[i], D[jj]);
                        D[i] = lo; D[jj] = hi;
                    }
                if (lane == 0) {
                    #pragma unroll
                    for (int i = 1; i < 5; ++i) {
                        float cc = (D[i] < EPSV) ? EPSV : D[i];
                        accW += 0.1f - sqrtf(cc) * expf(-cc / H2);
                    }
                }
            }
        }
    }

    #pragma unroll
    for (int off = 32; off >= 1; off >>= 1)
        accW += __shfl_down(accW, off, 64);
    if (lane == 0) atomicAdd(&blockAcc, accW);
    __syncthreads();
    if (tid == 0) atomicAdd(out, blockAcc * SCALE);
}

extern "C" void kernel_launch(void* const* d_in, const int* in_sizes, int n_in,
                              void* d_out, int out_size, void* d_ws, size_t ws_size,
                              hipStream_t stream) {
    const float* pred = (const float*)d_in[0];
    float* out = (float*)d_out;
    float4* sorted = (float4*)d_ws;
    int* cellStart = (int*)((char*)d_ws + (size_t)NB * NPTS * sizeof(float4));
    // out is zeroed inside bin_kernel (block 0) -- no separate memset launch.
    bin_kernel<<<dim3(NB), dim3(1024), 0, stream>>>(pred, sorted, cellStart, out);
    query_kernel<<<dim3(NB * 128), dim3(512), 0, stream>>>(sorted, cellStart, out);
}